// Round 2
// baseline (510.201 us; speedup 1.0000x reference)
//
#include <hip/hip_runtime.h>

// Problem constants (match reference)
#define B_SZ   8
#define NUMR   128            // num
#define L_SZ   (NUMR * NUMR)  // 16384
#define HH     8              // heads
#define DK     64
#define CC     512            // H*DK
#define EPSV   1e-8f

// ---------------------------------------------------------------------------
// Kernel A: cosine similarity + ReLU + per-(b,i,h) top-4 union.
// One block (512 thr = 8 waves) per (b,i). Each wave handles 16 j-rows:
// per row, lane loads 8 contiguous floats (2 x float4) of q and k; lane group
// [h*8, h*8+8) covers head h. 8-lane shuffle reduce -> cos-sim per head.
// Lanes 0..7 write the 8 head values to global attn (d_out, (b,i,j,h) layout)
// and to LDS (row stride 9 floats -> 2-way bank aliasing only, free).
// Then wave w does top-4 over j in [0,128) for head w from LDS and unions the
// winner columns into colmask (float 0/1, racing 1.0f stores are benign).
// ---------------------------------------------------------------------------
__global__ __launch_bounds__(512) void cos_topk_kernel(
    const float* __restrict__ q, const float* __restrict__ k,
    float* __restrict__ attn, float* __restrict__ colmask) {
  __shared__ float sA[NUMR][HH + 1];  // stride 9: banks (9*lane+h)%32, 2-way

  const int bi   = blockIdx.x;        // b*num + i
  const int wave = threadIdx.x >> 6;  // 0..7
  const int lane = threadIdx.x & 63;

  const size_t blockbase = (size_t)bi * NUMR * CC;

#pragma unroll 2
  for (int t = 0; t < 16; ++t) {
    const int j = wave * 16 + t;
    const size_t rowbase = blockbase + (size_t)j * CC + (size_t)lane * 8;
    const float4* qp = (const float4*)(q + rowbase);
    const float4* kp = (const float4*)(k + rowbase);
    const float4 a0 = qp[0], a1 = qp[1];
    const float4 b0 = kp[0], b1 = kp[1];

    float dot = a0.x * b0.x + a0.y * b0.y + a0.z * b0.z + a0.w * b0.w +
                a1.x * b1.x + a1.y * b1.y + a1.z * b1.z + a1.w * b1.w;
    float qq  = a0.x * a0.x + a0.y * a0.y + a0.z * a0.z + a0.w * a0.w +
                a1.x * a1.x + a1.y * a1.y + a1.z * a1.z + a1.w * a1.w;
    float kk  = b0.x * b0.x + b0.y * b0.y + b0.z * b0.z + b0.w * b0.w +
                b1.x * b1.x + b1.y * b1.y + b1.z * b1.z + b1.w * b1.w;

#pragma unroll
    for (int off = 1; off < 8; off <<= 1) {
      dot += __shfl_xor(dot, off, 64);
      qq  += __shfl_xor(qq,  off, 64);
      kk  += __shfl_xor(kk,  off, 64);
    }

    const float denom = fmaxf(sqrtf(qq) * sqrtf(kk), EPSV);
    const float val   = fmaxf(dot / denom, 0.0f);

    // lane l (l<8) picks up head l's value (resident on lanes l*8..l*8+7)
    const float r = __shfl(val, (lane & 7) * 8, 64);
    if (lane < HH) {
      sA[j][lane] = r;
      attn[((size_t)bi * NUMR + j) * HH + lane] = r;
    }
  }
  __syncthreads();

  // top-4 over j for head h = wave. lane holds j=lane and j=lane+64.
  // Tie-break: higher value wins; equal value -> lower index (lax.top_k set).
  float v0 = sA[lane][wave];
  float v1 = sA[lane + 64][wave];
#pragma unroll
  for (int rnd = 0; rnd < 4; ++rnd) {
    float bv;
    int bi_w;
    if (v1 > v0) { bv = v1; bi_w = lane + 64; } else { bv = v0; bi_w = lane; }
#pragma unroll
    for (int off = 1; off < 64; off <<= 1) {
      const float ov = __shfl_xor(bv, off, 64);
      const int   oi = __shfl_xor(bi_w, off, 64);
      if (ov > bv || (ov == bv && oi < bi_w)) { bv = ov; bi_w = oi; }
    }
    if (bi_w == lane)           v0 = -1.0f;
    else if (bi_w == lane + 64) v1 = -1.0f;
    if (lane == 0) colmask[bi_w] = 1.0f;  // racing identical stores: benign
  }
}

// ---------------------------------------------------------------------------
// Kernel C: out[b,i,j,h] *= roi[b,i,j] * colmask[j]  (in place on d_out)
// One thread per (b,i,j): 8 head values as 2 x float4.
// ---------------------------------------------------------------------------
__global__ __launch_bounds__(256) void apply_kernel(
    float* __restrict__ out, const float* __restrict__ roi,
    const float* __restrict__ colmask) {
  const int t = blockIdx.x * blockDim.x + threadIdx.x;  // (b*num+i)*num+j
  const float s = roi[t] * colmask[t & (NUMR - 1)];
  float4* p = (float4*)(out + (size_t)t * 8);
  float4 x0 = p[0], x1 = p[1];
  x0.x *= s; x0.y *= s; x0.z *= s; x0.w *= s;
  x1.x *= s; x1.y *= s; x1.z *= s; x1.w *= s;
  p[0] = x0;
  p[1] = x1;
}

extern "C" void kernel_launch(void* const* d_in, const int* in_sizes, int n_in,
                              void* d_out, int out_size, void* d_ws, size_t ws_size,
                              hipStream_t stream) {
  const float* q   = (const float*)d_in[0];  // (B, num, num, C) fp32
  const float* k   = (const float*)d_in[1];  // (B, num, num, C) fp32
  const float* roi = (const float*)d_in[2];  // (B, num, num)    fp32
  float* out = (float*)d_out;                // (B, num, num, H) fp32 == attn
  float* colmask = (float*)d_ws;             // 128 floats

  // zero the 128-entry column mask (ws is poisoned 0xAA before every launch)
  hipMemsetAsync(colmask, 0, NUMR * sizeof(float), stream);

  // Kernel A: one block per (b,i) -> 1024 blocks x 512 threads
  cos_topk_kernel<<<B_SZ * NUMR, 512, 0, stream>>>(q, k, out, colmask);

  // Kernel C: B*num*num threads -> 512 blocks x 256
  apply_kernel<<<(B_SZ * L_SZ) / 256, 256, 0, stream>>>(out, roi, colmask);
}